// Round 7
// baseline (402.889 us; speedup 1.0000x reference)
//
#include <hip/hip_runtime.h>
#include <hip/hip_cooperative_groups.h>

namespace cg = cooperative_groups;

#define B_  128
#define C_  256
#define H_  64
#define W_  64
#define J_  17
#define HP_ 32          // n_heads * n_points
#define HW_ (H_ * W_)
#define CG_ 2           // channels per gather task (32 KB per buffer)
#define GRID_ 512       // cooperative grid (2 blocks/CU)
#define TPB_  256
#define NTASK (B_ * (C_ / CG_))          // 16384
#define TASKS_PER_BLK (NTASK / GRID_)    // 32
#define PROJ_ROWS 8

// ---------------------------------------------------------------------------
// stage one (b, 2-channel) plane pair (32 KB) into an LDS buffer via
// global_load_lds width=16. 8 instrs/wave -> counted-vmcnt pipeline.
// ---------------------------------------------------------------------------
__device__ __forceinline__ void stage_task(const float* __restrict__ feat,
                                           int task, float* buf, int t) {
    const int b   = task >> 7;
    const int cgp = task & 127;
    const int wv  = t >> 6;
    const char* gsrc = (const char*)(feat + (size_t)(b * C_ + cgp * CG_) * HW_);
    #pragma unroll
    for (int i = 0; i < 8; ++i) {
        const size_t off = ((size_t)(i * 256 + wv * 64)) * 16;
        __builtin_amdgcn_global_load_lds(
            (const __attribute__((address_space(1))) void*)(gsrc + off + (size_t)(t & 63) * 16),
            (__attribute__((address_space(3))) void*)((char*)buf + off),
            16, 0, 0);
    }
}

// ---------------------------------------------------------------------------
// Fused cooperative kernel: pass12 -> grid.sync -> pipelined gather ->
// grid.sync -> proj.
// ---------------------------------------------------------------------------
__global__ __launch_bounds__(TPB_, 2)
void fused_kernel(const float* __restrict__ feat,    // [B,C,H,W]
                  const float* __restrict__ refpts,  // [B,J,2]
                  const float* __restrict__ Woff,    // [C,64]
                  const float* __restrict__ boff,    // [64]
                  const float* __restrict__ Ww,      // [C,32]
                  const float* __restrict__ bw,      // [32]
                  const float* __restrict__ Wout,    // [C,C]
                  const float* __restrict__ bout,    // [C]
                  int4*   __restrict__ meta_idx,     // [B*J*HP]
                  float4* __restrict__ meta_w,       // [B*J*HP]
                  float*  __restrict__ acc,          // [B,J,C]
                  float*  __restrict__ out)          // [B,J,C]
{
    __shared__ float lds[2 * CG_ * HW_];   // 2 x 32 KB
    cg::grid_group grid = cg::this_grid();

    const int blk = blockIdx.x;
    const int t   = threadIdx.x;
    const int wv  = t >> 6;
    const int ln  = t & 63;

    // ---- prologue: stage task r=0 into buf0 ----
    stage_task(feat, blk, lds, t);

    // ---- phase 1: pass12 (scratch lives in buf1, not staged yet) ----
    {
        float* scratch  = lds + CG_ * HW_;
        float* q_lds    = scratch;          // 256
        float* part_off = scratch + 256;    // 4*64
        float* part_w   = scratch + 512;    // 8*32
        float* off_lds  = scratch + 768;    // 64
        float* logit    = scratch + 832;    // 32

        const int nbj = (blk < (B_ * J_ - 4 * GRID_)) ? 5 : 4;  // 2176 = 4*512+128
        for (int r = 0; r < nbj; ++r) {
            const int bj = blk + r * GRID_;
            const int b  = bj / J_;
            const int j  = bj % J_;
            const int c  = t;

            const float rx = refpts[(b * J_ + j) * 2 + 0];
            const float ry = refpts[(b * J_ + j) * 2 + 1];

            // q sample (channel-strided; random-line bound)
            {
                const float* featbc = feat + (size_t)(b * C_ + c) * HW_;
                float ix = (rx + 1.0f) * (0.5f * W_) - 0.5f;
                float iy = (ry + 1.0f) * (0.5f * H_) - 0.5f;
                float x0f = floorf(ix), y0f = floorf(iy);
                int x0 = (int)x0f, y0 = (int)y0f;
                int x1 = x0 + 1,  y1 = y0 + 1;
                float wx1 = ix - x0f, wx0 = 1.0f - wx1;
                float wy1 = iy - y0f, wy0 = 1.0f - wy1;
                bool vx0 = (x0 >= 0) && (x0 < W_);
                bool vx1 = (x1 >= 0) && (x1 < W_);
                bool vy0 = (y0 >= 0) && (y0 < H_);
                bool vy1 = (y1 >= 0) && (y1 < H_);
                int x0c = min(max(x0, 0), W_ - 1), x1c = min(max(x1, 0), W_ - 1);
                int y0c = min(max(y0, 0), H_ - 1), y1c = min(max(y1, 0), H_ - 1);
                float v00 = (vx0 && vy0) ? featbc[y0c * W_ + x0c] : 0.0f;
                float v10 = (vx1 && vy0) ? featbc[y0c * W_ + x1c] : 0.0f;
                float v01 = (vx0 && vy1) ? featbc[y1c * W_ + x0c] : 0.0f;
                float v11 = (vx1 && vy1) ? featbc[y1c * W_ + x1c] : 0.0f;
                q_lds[c] = v00 * (wx0 * wy0) + v10 * (wx1 * wy0)
                         + v01 * (wx0 * wy1) + v11 * (wx1 * wy1);
            }
            __syncthreads();

            // branch-free k-split GEMVs
            {
                float aoff = 0.0f;
                #pragma unroll 8
                for (int i = 0; i < 64; ++i) {
                    const int k = wv * 64 + i;
                    aoff += q_lds[k] * Woff[k * 64 + ln];
                }
                part_off[wv * 64 + ln] = aoff;
                const int h = ln >> 5, p = ln & 31;
                float aw = 0.0f;
                #pragma unroll 8
                for (int i = 0; i < 32; ++i) {
                    const int k = wv * 64 + h * 32 + i;
                    aw += q_lds[k] * Ww[k * 32 + p];
                }
                part_w[(wv * 2 + h) * 32 + p] = aw;
            }
            __syncthreads();
            if (t < 64) {
                off_lds[t] = boff[t] + part_off[t] + part_off[64 + t]
                           + part_off[128 + t] + part_off[192 + t];
            } else if (t < 96) {
                const int p = t - 64;
                float s = bw[p];
                #pragma unroll
                for (int sidx = 0; sidx < 8; ++sidx) s += part_w[sidx * 32 + p];
                logit[p] = s;
            }
            __syncthreads();

            // softmax + grid + corner metadata
            if (t < HP_) {
                float l = logit[t];
                float m = l;
                #pragma unroll
                for (int mask = 16; mask >= 1; mask >>= 1) m = fmaxf(m, __shfl_xor(m, mask));
                float e = expf(l - m);
                float s = e;
                #pragma unroll
                for (int mask = 16; mask >= 1; mask >>= 1) s += __shfl_xor(s, mask);
                const float ww = e / s;

                float gx = fminf(fmaxf(rx + off_lds[2 * t + 0], -1.0f), 1.0f);
                float gy = fminf(fmaxf(ry + off_lds[2 * t + 1], -1.0f), 1.0f);
                float ix = (gx + 1.0f) * (0.5f * W_) - 0.5f;
                float iy = (gy + 1.0f) * (0.5f * H_) - 0.5f;
                float x0f = floorf(ix), y0f = floorf(iy);
                int x0 = (int)x0f, y0 = (int)y0f;
                int x1 = x0 + 1,  y1 = y0 + 1;
                float wx1 = ix - x0f, wx0 = 1.0f - wx1;
                float wy1 = iy - y0f, wy0 = 1.0f - wy1;
                float v00 = (float)((x0 >= 0) && (x0 < W_) && (y0 >= 0) && (y0 < H_));
                float v10 = (float)((x1 >= 0) && (x1 < W_) && (y0 >= 0) && (y0 < H_));
                float v01 = (float)((x0 >= 0) && (x0 < W_) && (y1 >= 0) && (y1 < H_));
                float v11 = (float)((x1 >= 0) && (x1 < W_) && (y1 >= 0) && (y1 < H_));
                int x0c = min(max(x0, 0), W_ - 1), x1c = min(max(x1, 0), W_ - 1);
                int y0c = min(max(y0, 0), H_ - 1), y1c = min(max(y1, 0), H_ - 1);
                const int mi = bj * HP_ + t;
                meta_idx[mi] = make_int4(y0c * W_ + x0c, y0c * W_ + x1c,
                                         y1c * W_ + x0c, y1c * W_ + x1c);
                meta_w[mi] = make_float4(ww * wx0 * wy0 * v00, ww * wx1 * wy0 * v10,
                                         ww * wx0 * wy1 * v01, ww * wx1 * wy1 * v11);
            }
            __syncthreads();
        }
    }

    __threadfence();
    grid.sync();

    // ---- phase 2: persistent pipelined gather ----
    const int p    = ln & 31;
    const int half = ln >> 5;
    for (int r = 0; r < TASKS_PER_BLK; ++r) {
        const int task = blk + r * GRID_;
        const int b    = task >> 7;
        const int c0   = (task & 127) * CG_;
        float* cur = lds + (r & 1) * (CG_ * HW_);

        // meta prefetch for CUR (up to 6 vmem instrs/wave)
        int4   id_r[3];
        float4 w_r[3];
        #pragma unroll
        for (int iter = 0; iter < 3; ++iter) {
            const int j = iter * 8 + wv * 2 + half;
            if (j < J_) {
                const int mi = (b * J_ + j) * HP_ + p;
                id_r[iter] = meta_idx[mi];
                w_r[iter]  = meta_w[mi];
            } else {
                id_r[iter] = make_int4(0, 0, 0, 0);
                w_r[iter]  = make_float4(0.f, 0.f, 0.f, 0.f);
            }
        }

        // stage NEXT, then counted wait: everything older than the newest
        // 14 vmem ops (6 meta + 8 stage_next) — i.e. stage_cur — retired.
        if (r + 1 < TASKS_PER_BLK) {
            stage_task(feat, task + GRID_, lds + ((r + 1) & 1) * (CG_ * HW_), t);
            asm volatile("s_waitcnt vmcnt(14)" ::: "memory");
        } else {
            asm volatile("s_waitcnt vmcnt(0)" ::: "memory");
        }
        __syncthreads();

        #pragma unroll
        for (int iter = 0; iter < 3; ++iter) {
            const int j = iter * 8 + wv * 2 + half;
            const int4   id = id_r[iter];
            const float4 w  = w_r[iter];
            float pj0 = w.x * cur[id.x] + w.y * cur[id.y]
                      + w.z * cur[id.z] + w.w * cur[id.w];
            float pj1 = w.x * cur[HW_ + id.x] + w.y * cur[HW_ + id.y]
                      + w.z * cur[HW_ + id.z] + w.w * cur[HW_ + id.w];
            #pragma unroll
            for (int mask = 16; mask >= 1; mask >>= 1) {
                pj0 += __shfl_xor(pj0, mask);
                pj1 += __shfl_xor(pj1, mask);
            }
            if (j < J_ && p == 0) {
                float2* dst = (float2*)(acc + ((size_t)(b * J_ + j)) * C_ + c0);
                *dst = make_float2(pj0, pj1);
            }
        }
        __syncthreads();
    }

    __threadfence();
    grid.sync();

    // ---- phase 3: output projection (272 active blocks, 8 rows each) ----
    if (blk < (B_ * J_) / PROJ_ROWS) {
        float* a_lds = lds;   // [8][256] = 8 KB
        const int bj0 = blk * PROJ_ROWS;
        #pragma unroll
        for (int r = 0; r < PROJ_ROWS; ++r)
            a_lds[r * C_ + t] = acc[(size_t)(bj0 + r) * C_ + t];
        __syncthreads();

        float o[PROJ_ROWS];
        const float bb = bout[t];
        #pragma unroll
        for (int r = 0; r < PROJ_ROWS; ++r) o[r] = bb;
        #pragma unroll 4
        for (int k = 0; k < C_; ++k) {
            const float wvv = Wout[(size_t)k * C_ + t];
            #pragma unroll
            for (int r = 0; r < PROJ_ROWS; ++r)
                o[r] += a_lds[r * C_ + k] * wvv;
        }
        #pragma unroll
        for (int r = 0; r < PROJ_ROWS; ++r)
            out[(size_t)(bj0 + r) * C_ + t] = o[r];
    }
}

// ===========================================================================
// Fallback 3-kernel path (round-6 proven implementation)
// ===========================================================================
__global__ __launch_bounds__(256)
void pass12_kernel(const float* __restrict__ feat,
                   const float* __restrict__ refpts,
                   const float* __restrict__ Woff,
                   const float* __restrict__ boff,
                   const float* __restrict__ Ww,
                   const float* __restrict__ bw,
                   int4*  __restrict__ meta_idx,
                   float4* __restrict__ meta_w)
{
    __shared__ float q_lds[C_];
    __shared__ float part_off[4][64];
    __shared__ float part_w[8][32];
    __shared__ float off_lds[2 * HP_];
    __shared__ float logit_lds[HP_];

    const int bj = blockIdx.x;
    const int b  = bj / J_;
    const int j  = bj % J_;
    const int c  = threadIdx.x;

    const float rx = refpts[(b * J_ + j) * 2 + 0];
    const float ry = refpts[(b * J_ + j) * 2 + 1];

    {
        const float* featbc = feat + (size_t)(b * C_ + c) * HW_;
        float ix = (rx + 1.0f) * (0.5f * W_) - 0.5f;
        float iy = (ry + 1.0f) * (0.5f * H_) - 0.5f;
        float x0f = floorf(ix), y0f = floorf(iy);
        int x0 = (int)x0f, y0 = (int)y0f;
        int x1 = x0 + 1,  y1 = y0 + 1;
        float wx1 = ix - x0f, wx0 = 1.0f - wx1;
        float wy1 = iy - y0f, wy0 = 1.0f - wy1;
        bool vx0 = (x0 >= 0) && (x0 < W_);
        bool vx1 = (x1 >= 0) && (x1 < W_);
        bool vy0 = (y0 >= 0) && (y0 < H_);
        bool vy1 = (y1 >= 0) && (y1 < H_);
        int x0c = min(max(x0, 0), W_ - 1), x1c = min(max(x1, 0), W_ - 1);
        int y0c = min(max(y0, 0), H_ - 1), y1c = min(max(y1, 0), H_ - 1);
        float v00 = (vx0 && vy0) ? featbc[y0c * W_ + x0c] : 0.0f;
        float v10 = (vx1 && vy0) ? featbc[y0c * W_ + x1c] : 0.0f;
        float v01 = (vx0 && vy1) ? featbc[y1c * W_ + x0c] : 0.0f;
        float v11 = (vx1 && vy1) ? featbc[y1c * W_ + x1c] : 0.0f;
        q_lds[c] = v00 * (wx0 * wy0) + v10 * (wx1 * wy0)
                 + v01 * (wx0 * wy1) + v11 * (wx1 * wy1);
    }
    __syncthreads();

    {
        const int wv = c >> 6, ln = c & 63;
        float aoff = 0.0f;
        #pragma unroll 8
        for (int i = 0; i < 64; ++i) {
            const int k = wv * 64 + i;
            aoff += q_lds[k] * Woff[k * 64 + ln];
        }
        part_off[wv][ln] = aoff;
        const int h = ln >> 5, p = ln & 31;
        float aw = 0.0f;
        #pragma unroll 8
        for (int i = 0; i < 32; ++i) {
            const int k = wv * 64 + h * 32 + i;
            aw += q_lds[k] * Ww[k * 32 + p];
        }
        part_w[wv * 2 + h][p] = aw;
    }
    __syncthreads();
    if (c < 64) {
        off_lds[c] = boff[c] + part_off[0][c] + part_off[1][c]
                   + part_off[2][c] + part_off[3][c];
    } else if (c < 96) {
        const int p = c - 64;
        float s = bw[p];
        #pragma unroll
        for (int sidx = 0; sidx < 8; ++sidx) s += part_w[sidx][p];
        logit_lds[p] = s;
    }
    __syncthreads();

    if (c < HP_) {
        float l = logit_lds[c];
        float m = l;
        #pragma unroll
        for (int mask = 16; mask >= 1; mask >>= 1) m = fmaxf(m, __shfl_xor(m, mask));
        float e = expf(l - m);
        float s = e;
        #pragma unroll
        for (int mask = 16; mask >= 1; mask >>= 1) s += __shfl_xor(s, mask);
        const float ww = e / s;

        float gx = fminf(fmaxf(rx + off_lds[2 * c + 0], -1.0f), 1.0f);
        float gy = fminf(fmaxf(ry + off_lds[2 * c + 1], -1.0f), 1.0f);
        float ix = (gx + 1.0f) * (0.5f * W_) - 0.5f;
        float iy = (gy + 1.0f) * (0.5f * H_) - 0.5f;
        float x0f = floorf(ix), y0f = floorf(iy);
        int x0 = (int)x0f, y0 = (int)y0f;
        int x1 = x0 + 1,  y1 = y0 + 1;
        float wx1 = ix - x0f, wx0 = 1.0f - wx1;
        float wy1 = iy - y0f, wy0 = 1.0f - wy1;
        float v00 = (float)((x0 >= 0) && (x0 < W_) && (y0 >= 0) && (y0 < H_));
        float v10 = (float)((x1 >= 0) && (x1 < W_) && (y0 >= 0) && (y0 < H_));
        float v01 = (float)((x0 >= 0) && (x0 < W_) && (y1 >= 0) && (y1 < H_));
        float v11 = (float)((x1 >= 0) && (x1 < W_) && (y1 >= 0) && (y1 < H_));
        int x0c = min(max(x0, 0), W_ - 1), x1c = min(max(x1, 0), W_ - 1);
        int y0c = min(max(y0, 0), H_ - 1), y1c = min(max(y1, 0), H_ - 1);
        const int mi = bj * HP_ + c;
        meta_idx[mi] = make_int4(y0c * W_ + x0c, y0c * W_ + x1c,
                                 y1c * W_ + x0c, y1c * W_ + x1c);
        meta_w[mi] = make_float4(ww * wx0 * wy0 * v00, ww * wx1 * wy0 * v10,
                                 ww * wx0 * wy1 * v01, ww * wx1 * wy1 * v11);
    }
}

__global__ __launch_bounds__(512)
void gather_kernel(const float* __restrict__ feat,
                   const int4*  __restrict__ meta_idx,
                   const float4* __restrict__ meta_w,
                   float* __restrict__ acc)
{
    __shared__ float plane[4 * HW_];   // 64 KB (CG=4 fallback)

    const int blk = blockIdx.x;
    const int b   = blk >> 6;
    const int cg  = blk & 63;
    const int c0  = cg * 4;
    const int t   = threadIdx.x;
    const int wv  = t >> 6;
    const int ln  = t & 63;

    {
        const char* gsrc = (const char*)(feat + (size_t)(b * C_ + c0) * HW_);
        #pragma unroll
        for (int i = 0; i < 8; ++i) {
            const size_t off = ((size_t)(i * 512 + wv * 64)) * 16;
            __builtin_amdgcn_global_load_lds(
                (const __attribute__((address_space(1))) void*)(gsrc + off + (size_t)ln * 16),
                (__attribute__((address_space(3))) void*)((char*)plane + off),
                16, 0, 0);
        }
    }

    const int p    = ln & 31;
    const int half = ln >> 5;
    int4   id_r[2];
    float4 w_r[2];
    #pragma unroll
    for (int iter = 0; iter < 2; ++iter) {
        const int j = iter * 16 + wv * 2 + half;
        if (j < J_) {
            const int mi = (b * J_ + j) * HP_ + p;
            id_r[iter] = meta_idx[mi];
            w_r[iter]  = meta_w[mi];
        } else {
            id_r[iter] = make_int4(0, 0, 0, 0);
            w_r[iter]  = make_float4(0.f, 0.f, 0.f, 0.f);
        }
    }
    __syncthreads();

    #pragma unroll
    for (int iter = 0; iter < 2; ++iter) {
        const int j = iter * 16 + wv * 2 + half;
        const int4   id = id_r[iter];
        const float4 w  = w_r[iter];
        float pj0 = w.x * plane[0 * HW_ + id.x] + w.y * plane[0 * HW_ + id.y]
                  + w.z * plane[0 * HW_ + id.z] + w.w * plane[0 * HW_ + id.w];
        float pj1 = w.x * plane[1 * HW_ + id.x] + w.y * plane[1 * HW_ + id.y]
                  + w.z * plane[1 * HW_ + id.z] + w.w * plane[1 * HW_ + id.w];
        float pj2 = w.x * plane[2 * HW_ + id.x] + w.y * plane[2 * HW_ + id.y]
                  + w.z * plane[2 * HW_ + id.z] + w.w * plane[2 * HW_ + id.w];
        float pj3 = w.x * plane[3 * HW_ + id.x] + w.y * plane[3 * HW_ + id.y]
                  + w.z * plane[3 * HW_ + id.z] + w.w * plane[3 * HW_ + id.w];
        #pragma unroll
        for (int mask = 16; mask >= 1; mask >>= 1) {
            pj0 += __shfl_xor(pj0, mask);
            pj1 += __shfl_xor(pj1, mask);
            pj2 += __shfl_xor(pj2, mask);
            pj3 += __shfl_xor(pj3, mask);
        }
        if (j < J_ && p == 0) {
            float4* dst = (float4*)(acc + ((size_t)(b * J_ + j)) * C_ + c0);
            *dst = make_float4(pj0, pj1, pj2, pj3);
        }
    }
}

__global__ __launch_bounds__(256)
void proj_kernel(const float* __restrict__ acc,
                 const float* __restrict__ Wout,
                 const float* __restrict__ bout,
                 float* __restrict__ out)
{
    __shared__ float a_lds[PROJ_ROWS][C_];
    const int bj0 = blockIdx.x * PROJ_ROWS;
    const int t   = threadIdx.x;

    #pragma unroll
    for (int r = 0; r < PROJ_ROWS; ++r)
        a_lds[r][t] = acc[(size_t)(bj0 + r) * C_ + t];
    __syncthreads();

    float o[PROJ_ROWS];
    const float bb = bout[t];
    #pragma unroll
    for (int r = 0; r < PROJ_ROWS; ++r) o[r] = bb;
    #pragma unroll 4
    for (int k = 0; k < C_; ++k) {
        const float wvv = Wout[(size_t)k * C_ + t];
        #pragma unroll
        for (int r = 0; r < PROJ_ROWS; ++r)
            o[r] += a_lds[r][k] * wvv;
    }
    #pragma unroll
    for (int r = 0; r < PROJ_ROWS; ++r)
        out[(size_t)(bj0 + r) * C_ + t] = o[r];
}

extern "C" void kernel_launch(void* const* d_in, const int* in_sizes, int n_in,
                              void* d_out, int out_size, void* d_ws, size_t ws_size,
                              hipStream_t stream) {
    const float* feat   = (const float*)d_in[0];
    const float* refpts = (const float*)d_in[1];
    const float* Woff   = (const float*)d_in[2];
    const float* boff   = (const float*)d_in[3];
    const float* Ww     = (const float*)d_in[4];
    const float* bw     = (const float*)d_in[5];
    const float* Wout   = (const float*)d_in[6];
    const float* bout   = (const float*)d_in[7];
    float* out = (float*)d_out;

    const size_t n_meta    = (size_t)B_ * J_ * HP_;
    const size_t idx_bytes = n_meta * sizeof(int4);
    const size_t w_bytes   = n_meta * sizeof(float4);
    const size_t acc_bytes = (size_t)B_ * J_ * C_ * sizeof(float);
    if (ws_size < idx_bytes + w_bytes + acc_bytes) return;  // ws always ample per harness

    char* ws = (char*)d_ws;
    int4*   meta_idx = (int4*)ws;
    float4* meta_w   = (float4*)(ws + idx_bytes);
    float*  acc      = (float*)(ws + idx_bytes + w_bytes);

    // Co-residency check for the cooperative path (host-side query, graph-safe)
    int nb = 0;
    bool coop = (hipOccupancyMaxActiveBlocksPerMultiprocessor(
                     &nb, (const void*)fused_kernel, TPB_, 0) == hipSuccess) && nb >= 2;

    if (coop) {
        void* args[] = {(void*)&feat, (void*)&refpts, (void*)&Woff, (void*)&boff,
                        (void*)&Ww,   (void*)&bw,     (void*)&Wout, (void*)&bout,
                        (void*)&meta_idx, (void*)&meta_w, (void*)&acc, (void*)&out};
        hipError_t e = hipLaunchCooperativeKernel((const void*)fused_kernel,
                                                  dim3(GRID_), dim3(TPB_),
                                                  args, 0, stream);
        if (e == hipSuccess) return;
    }

    // Fallback: proven 3-kernel path
    pass12_kernel<<<dim3(B_ * J_), dim3(256), 0, stream>>>(
        feat, refpts, Woff, boff, Ww, bw, meta_idx, meta_w);
    gather_kernel<<<dim3(B_ * 64), dim3(512), 0, stream>>>(
        feat, meta_idx, meta_w, acc);
    proj_kernel<<<dim3((B_ * J_) / PROJ_ROWS), dim3(256), 0, stream>>>(
        acc, Wout, bout, out);
}

// Round 8
// 180.228 us; speedup vs baseline: 2.2354x; 2.2354x over previous
//
#include <hip/hip_runtime.h>

#define B_  128
#define C_  256
#define H_  64
#define W_  64
#define J_  17
#define HP_ 32          // n_heads * n_points
#define HW_ (H_ * W_)
#define CG_ 2           // channels per gather task (32 KB per LDS buffer)
#define GBLK_ 2048      // persistent gather blocks
#define NTASK (B_ * (C_ / CG_))            // 16384
#define TASKS_PER_BLK (NTASK / GBLK_)      // 8
#define PROJ_ROWS 8

// ---------------------------------------------------------------------------
// Pass 1+2: per (b,j) — sample q at ref point, branch-free k-split GEMVs,
// softmax, emit per-(b,j,p) corner metadata.  (round-6 proven version)
// ---------------------------------------------------------------------------
__global__ __launch_bounds__(256)
void pass12_kernel(const float* __restrict__ feat,    // [B,C,H,W]
                   const float* __restrict__ refpts,  // [B,J,2]
                   const float* __restrict__ Woff,    // [C,64]
                   const float* __restrict__ boff,    // [64]
                   const float* __restrict__ Ww,      // [C,32]
                   const float* __restrict__ bw,      // [32]
                   int4*  __restrict__ meta_idx,      // [B*J*HP]
                   float4* __restrict__ meta_w)       // [B*J*HP]
{
    __shared__ float q_lds[C_];
    __shared__ float part_off[4][64];
    __shared__ float part_w[8][32];
    __shared__ float off_lds[2 * HP_];
    __shared__ float logit_lds[HP_];

    const int bj = blockIdx.x;
    const int b  = bj / J_;
    const int j  = bj % J_;
    const int c  = threadIdx.x;

    const float rx = refpts[(b * J_ + j) * 2 + 0];
    const float ry = refpts[(b * J_ + j) * 2 + 1];

    // ---- q sample (channel-strided; random-line bound) ----
    {
        const float* featbc = feat + (size_t)(b * C_ + c) * HW_;
        float ix = (rx + 1.0f) * (0.5f * W_) - 0.5f;
        float iy = (ry + 1.0f) * (0.5f * H_) - 0.5f;
        float x0f = floorf(ix), y0f = floorf(iy);
        int x0 = (int)x0f, y0 = (int)y0f;
        int x1 = x0 + 1,  y1 = y0 + 1;
        float wx1 = ix - x0f, wx0 = 1.0f - wx1;
        float wy1 = iy - y0f, wy0 = 1.0f - wy1;
        bool vx0 = (x0 >= 0) && (x0 < W_);
        bool vx1 = (x1 >= 0) && (x1 < W_);
        bool vy0 = (y0 >= 0) && (y0 < H_);
        bool vy1 = (y1 >= 0) && (y1 < H_);
        int x0c = min(max(x0, 0), W_ - 1), x1c = min(max(x1, 0), W_ - 1);
        int y0c = min(max(y0, 0), H_ - 1), y1c = min(max(y1, 0), H_ - 1);
        float v00 = (vx0 && vy0) ? featbc[y0c * W_ + x0c] : 0.0f;
        float v10 = (vx1 && vy0) ? featbc[y0c * W_ + x1c] : 0.0f;
        float v01 = (vx0 && vy1) ? featbc[y1c * W_ + x0c] : 0.0f;
        float v11 = (vx1 && vy1) ? featbc[y1c * W_ + x1c] : 0.0f;
        q_lds[c] = v00 * (wx0 * wy0) + v10 * (wx1 * wy0)
                 + v01 * (wx0 * wy1) + v11 * (wx1 * wy1);
    }
    __syncthreads();

    // ---- branch-free k-split GEMVs ----
    {
        const int wv = c >> 6, ln = c & 63;
        float aoff = 0.0f;
        #pragma unroll 8
        for (int i = 0; i < 64; ++i) {
            const int k = wv * 64 + i;
            aoff += q_lds[k] * Woff[k * 64 + ln];
        }
        part_off[wv][ln] = aoff;
        const int h = ln >> 5, p = ln & 31;
        float aw = 0.0f;
        #pragma unroll 8
        for (int i = 0; i < 32; ++i) {
            const int k = wv * 64 + h * 32 + i;
            aw += q_lds[k] * Ww[k * 32 + p];
        }
        part_w[wv * 2 + h][p] = aw;
    }
    __syncthreads();
    if (c < 64) {
        off_lds[c] = boff[c] + part_off[0][c] + part_off[1][c]
                   + part_off[2][c] + part_off[3][c];
    } else if (c < 96) {
        const int p = c - 64;
        float s = bw[p];
        #pragma unroll
        for (int sidx = 0; sidx < 8; ++sidx) s += part_w[sidx][p];
        logit_lds[p] = s;
    }
    __syncthreads();

    // ---- softmax + grid + corner metadata ----
    if (c < HP_) {
        float l = logit_lds[c];
        float m = l;
        #pragma unroll
        for (int mask = 16; mask >= 1; mask >>= 1) m = fmaxf(m, __shfl_xor(m, mask));
        float e = expf(l - m);
        float s = e;
        #pragma unroll
        for (int mask = 16; mask >= 1; mask >>= 1) s += __shfl_xor(s, mask);
        const float ww = e / s;

        float gx = fminf(fmaxf(rx + off_lds[2 * c + 0], -1.0f), 1.0f);
        float gy = fminf(fmaxf(ry + off_lds[2 * c + 1], -1.0f), 1.0f);
        float ix = (gx + 1.0f) * (0.5f * W_) - 0.5f;
        float iy = (gy + 1.0f) * (0.5f * H_) - 0.5f;
        float x0f = floorf(ix), y0f = floorf(iy);
        int x0 = (int)x0f, y0 = (int)y0f;
        int x1 = x0 + 1,  y1 = y0 + 1;
        float wx1 = ix - x0f, wx0 = 1.0f - wx1;
        float wy1 = iy - y0f, wy0 = 1.0f - wy1;
        float v00 = (float)((x0 >= 0) && (x0 < W_) && (y0 >= 0) && (y0 < H_));
        float v10 = (float)((x1 >= 0) && (x1 < W_) && (y0 >= 0) && (y0 < H_));
        float v01 = (float)((x0 >= 0) && (x0 < W_) && (y1 >= 0) && (y1 < H_));
        float v11 = (float)((x1 >= 0) && (x1 < W_) && (y1 >= 0) && (y1 < H_));
        int x0c = min(max(x0, 0), W_ - 1), x1c = min(max(x1, 0), W_ - 1);
        int y0c = min(max(y0, 0), H_ - 1), y1c = min(max(y1, 0), H_ - 1);
        const int mi = bj * HP_ + c;
        meta_idx[mi] = make_int4(y0c * W_ + x0c, y0c * W_ + x1c,
                                 y1c * W_ + x0c, y1c * W_ + x1c);
        meta_w[mi] = make_float4(ww * wx0 * wy0 * v00, ww * wx1 * wy0 * v10,
                                 ww * wx0 * wy1 * v01, ww * wx1 * wy1 * v11);
    }
}

// ---------------------------------------------------------------------------
// stage one (b, 2-channel) plane pair (32 KB) into an LDS buffer via
// global_load_lds width=16. 8 instrs/thread.
// ---------------------------------------------------------------------------
__device__ __forceinline__ void stage_task(const float* __restrict__ feat,
                                           int task, float* buf, int t) {
    const int b   = task >> 7;           // / 128
    const int cgp = task & 127;
    const int wv  = t >> 6;
    const int ln  = t & 63;
    const char* gsrc = (const char*)(feat + (size_t)(b * C_ + cgp * CG_) * HW_);
    #pragma unroll
    for (int i = 0; i < 8; ++i) {
        const size_t off = ((size_t)(i * 256 + wv * 64)) * 16;
        __builtin_amdgcn_global_load_lds(
            (const __attribute__((address_space(1))) void*)(gsrc + off + (size_t)ln * 16),
            (__attribute__((address_space(3))) void*)((char*)buf + off),
            16, 0, 0);
    }
}

// ---------------------------------------------------------------------------
// Pass 3: persistent double-buffered gather. Per task:
//   meta (oldest vmem) -> stage NEXT -> gather CUR (meta wait = vmcnt(8),
//   stage stays in flight under gather) -> __syncthreads (drain residual).
// ---------------------------------------------------------------------------
__global__ __launch_bounds__(256)
void gather_kernel(const float* __restrict__ feat,      // [B,C,H,W]
                   const int4*  __restrict__ meta_idx,  // [B*J*HP]
                   const float4* __restrict__ meta_w,   // [B*J*HP]
                   float* __restrict__ acc)             // [B,J,C]
{
    __shared__ float lds[2 * CG_ * HW_];   // 2 x 32 KB

    const int blk = blockIdx.x;
    const int t   = threadIdx.x;
    const int wv  = t >> 6;
    const int ln  = t & 63;
    const int p    = ln & 31;
    const int half = ln >> 5;

    const int task0 = blk * TASKS_PER_BLK;

    // prologue: stage first task, drain, barrier
    stage_task(feat, task0, lds, t);
    __syncthreads();

    #pragma unroll 1
    for (int r = 0; r < TASKS_PER_BLK; ++r) {
        const int task = task0 + r;
        const int b    = task >> 7;
        const int c0   = (task & 127) * CG_;
        float* cur = lds + (r & 1) * (CG_ * HW_);

        // ---- meta loads FIRST (become the oldest outstanding vmem) ----
        int4   id_r[3];
        float4 w_r[3];
        #pragma unroll
        for (int iter = 0; iter < 3; ++iter) {
            const int j = iter * 8 + wv * 2 + half;
            if (j < J_) {
                const int mi = (b * J_ + j) * HP_ + p;
                id_r[iter] = meta_idx[mi];
                w_r[iter]  = meta_w[mi];
            } else {
                id_r[iter] = make_int4(0, 0, 0, 0);
                w_r[iter]  = make_float4(0.f, 0.f, 0.f, 0.f);
            }
        }
        __builtin_amdgcn_sched_barrier(0);   // pin: meta before stage

        // ---- stage NEXT task into the other buffer (stays in flight) ----
        if (r + 1 < TASKS_PER_BLK)
            stage_task(feat, task + 1, lds + ((r + 1) & 1) * (CG_ * HW_), t);
        __builtin_amdgcn_sched_barrier(0);   // pin: stage before gather

        // ---- gather CUR from LDS (meta wait leaves stage outstanding) ----
        #pragma unroll
        for (int iter = 0; iter < 3; ++iter) {
            const int j = iter * 8 + wv * 2 + half;
            const int4   id = id_r[iter];
            const float4 w  = w_r[iter];
            float pj0 = w.x * cur[id.x] + w.y * cur[id.y]
                      + w.z * cur[id.z] + w.w * cur[id.w];
            float pj1 = w.x * cur[HW_ + id.x] + w.y * cur[HW_ + id.y]
                      + w.z * cur[HW_ + id.z] + w.w * cur[HW_ + id.w];
            #pragma unroll
            for (int mask = 16; mask >= 1; mask >>= 1) {
                pj0 += __shfl_xor(pj0, mask);
                pj1 += __shfl_xor(pj1, mask);
            }
            if (j < J_ && p == 0) {
                float2* dst = (float2*)(acc + ((size_t)(b * J_ + j)) * C_ + c0);
                *dst = make_float2(pj0, pj1);
            }
        }

        // ---- single per-task barrier: drains residual of stage r+1 and
        //      protects buf[(r+1)&1] (last read in task r-1) ----
        __syncthreads();
    }
}

// ---------------------------------------------------------------------------
// Pass 4: tiled output projection — 8 bj rows per block, Wout reuse x8.
// ---------------------------------------------------------------------------
__global__ __launch_bounds__(256)
void proj_kernel(const float* __restrict__ acc,   // [B*J, C]
                 const float* __restrict__ Wout,  // [C, C]
                 const float* __restrict__ bout,  // [C]
                 float* __restrict__ out)         // [B*J, C]
{
    __shared__ float a_lds[PROJ_ROWS][C_];
    const int bj0 = blockIdx.x * PROJ_ROWS;
    const int t   = threadIdx.x;

    #pragma unroll
    for (int r = 0; r < PROJ_ROWS; ++r)
        a_lds[r][t] = acc[(size_t)(bj0 + r) * C_ + t];
    __syncthreads();

    float o[PROJ_ROWS];
    const float bb = bout[t];
    #pragma unroll
    for (int r = 0; r < PROJ_ROWS; ++r) o[r] = bb;
    #pragma unroll 4
    for (int k = 0; k < C_; ++k) {
        const float wvv = Wout[(size_t)k * C_ + t];
        #pragma unroll
        for (int r = 0; r < PROJ_ROWS; ++r)
            o[r] += a_lds[r][k] * wvv;
    }
    #pragma unroll
    for (int r = 0; r < PROJ_ROWS; ++r)
        out[(size_t)(bj0 + r) * C_ + t] = o[r];
}

extern "C" void kernel_launch(void* const* d_in, const int* in_sizes, int n_in,
                              void* d_out, int out_size, void* d_ws, size_t ws_size,
                              hipStream_t stream) {
    const float* feat   = (const float*)d_in[0];
    const float* refpts = (const float*)d_in[1];
    const float* Woff   = (const float*)d_in[2];
    const float* boff   = (const float*)d_in[3];
    const float* Ww     = (const float*)d_in[4];
    const float* bw     = (const float*)d_in[5];
    const float* Wout   = (const float*)d_in[6];
    const float* bout   = (const float*)d_in[7];
    float* out = (float*)d_out;

    const size_t n_meta    = (size_t)B_ * J_ * HP_;
    const size_t idx_bytes = n_meta * sizeof(int4);
    const size_t w_bytes   = n_meta * sizeof(float4);

    char* ws = (char*)d_ws;
    int4*   meta_idx = (int4*)ws;
    float4* meta_w   = (float4*)(ws + idx_bytes);
    float*  acc      = (float*)(ws + idx_bytes + w_bytes);

    pass12_kernel<<<dim3(B_ * J_), dim3(256), 0, stream>>>(
        feat, refpts, Woff, boff, Ww, bw, meta_idx, meta_w);
    gather_kernel<<<dim3(GBLK_), dim3(256), 0, stream>>>(
        feat, meta_idx, meta_w, acc);
    proj_kernel<<<dim3((B_ * J_) / PROJ_ROWS), dim3(256), 0, stream>>>(
        acc, Wout, bout, out);
}

// Round 9
// 154.811 us; speedup vs baseline: 2.6025x; 1.1642x over previous
//
#include <hip/hip_runtime.h>

#define B_  128
#define C_  256
#define H_  64
#define W_  64
#define J_  17
#define HP_ 32          // n_heads * n_points
#define HW_ (H_ * W_)
#define CG_ 4           // channels per gather block (64 KB LDS -> 2 blocks/CU)
#define PROJ_ROWS 8

// ---------------------------------------------------------------------------
// Pass 1+2: per (b,j) — sample q at ref point, branch-free k-split GEMVs,
// softmax, emit per-(b,j,p) corner metadata.  (round-6 proven version)
// ---------------------------------------------------------------------------
__global__ __launch_bounds__(256)
void pass12_kernel(const float* __restrict__ feat,    // [B,C,H,W]
                   const float* __restrict__ refpts,  // [B,J,2]
                   const float* __restrict__ Woff,    // [C,64]
                   const float* __restrict__ boff,    // [64]
                   const float* __restrict__ Ww,      // [C,32]
                   const float* __restrict__ bw,      // [32]
                   int4*  __restrict__ meta_idx,      // [B*J*HP]
                   float4* __restrict__ meta_w)       // [B*J*HP]
{
    __shared__ float q_lds[C_];
    __shared__ float part_off[4][64];
    __shared__ float part_w[8][32];
    __shared__ float off_lds[2 * HP_];
    __shared__ float logit_lds[HP_];

    const int bj = blockIdx.x;
    const int b  = bj / J_;
    const int j  = bj % J_;
    const int c  = threadIdx.x;

    const float rx = refpts[(b * J_ + j) * 2 + 0];
    const float ry = refpts[(b * J_ + j) * 2 + 1];

    // ---- q sample (channel-strided; random-line bound) ----
    {
        const float* featbc = feat + (size_t)(b * C_ + c) * HW_;
        float ix = (rx + 1.0f) * (0.5f * W_) - 0.5f;
        float iy = (ry + 1.0f) * (0.5f * H_) - 0.5f;
        float x0f = floorf(ix), y0f = floorf(iy);
        int x0 = (int)x0f, y0 = (int)y0f;
        int x1 = x0 + 1,  y1 = y0 + 1;
        float wx1 = ix - x0f, wx0 = 1.0f - wx1;
        float wy1 = iy - y0f, wy0 = 1.0f - wy1;
        bool vx0 = (x0 >= 0) && (x0 < W_);
        bool vx1 = (x1 >= 0) && (x1 < W_);
        bool vy0 = (y0 >= 0) && (y0 < H_);
        bool vy1 = (y1 >= 0) && (y1 < H_);
        int x0c = min(max(x0, 0), W_ - 1), x1c = min(max(x1, 0), W_ - 1);
        int y0c = min(max(y0, 0), H_ - 1), y1c = min(max(y1, 0), H_ - 1);
        float v00 = (vx0 && vy0) ? featbc[y0c * W_ + x0c] : 0.0f;
        float v10 = (vx1 && vy0) ? featbc[y0c * W_ + x1c] : 0.0f;
        float v01 = (vx0 && vy1) ? featbc[y1c * W_ + x0c] : 0.0f;
        float v11 = (vx1 && vy1) ? featbc[y1c * W_ + x1c] : 0.0f;
        q_lds[c] = v00 * (wx0 * wy0) + v10 * (wx1 * wy0)
                 + v01 * (wx0 * wy1) + v11 * (wx1 * wy1);
    }
    __syncthreads();

    // ---- branch-free k-split GEMVs ----
    {
        const int wv = c >> 6, ln = c & 63;
        float aoff = 0.0f;
        #pragma unroll 8
        for (int i = 0; i < 64; ++i) {
            const int k = wv * 64 + i;
            aoff += q_lds[k] * Woff[k * 64 + ln];
        }
        part_off[wv][ln] = aoff;
        const int h = ln >> 5, p = ln & 31;
        float aw = 0.0f;
        #pragma unroll 8
        for (int i = 0; i < 32; ++i) {
            const int k = wv * 64 + h * 32 + i;
            aw += q_lds[k] * Ww[k * 32 + p];
        }
        part_w[wv * 2 + h][p] = aw;
    }
    __syncthreads();
    if (c < 64) {
        off_lds[c] = boff[c] + part_off[0][c] + part_off[1][c]
                   + part_off[2][c] + part_off[3][c];
    } else if (c < 96) {
        const int p = c - 64;
        float s = bw[p];
        #pragma unroll
        for (int sidx = 0; sidx < 8; ++sidx) s += part_w[sidx][p];
        logit_lds[p] = s;
    }
    __syncthreads();

    // ---- softmax + grid + corner metadata ----
    if (c < HP_) {
        float l = logit_lds[c];
        float m = l;
        #pragma unroll
        for (int mask = 16; mask >= 1; mask >>= 1) m = fmaxf(m, __shfl_xor(m, mask));
        float e = expf(l - m);
        float s = e;
        #pragma unroll
        for (int mask = 16; mask >= 1; mask >>= 1) s += __shfl_xor(s, mask);
        const float ww = e / s;

        float gx = fminf(fmaxf(rx + off_lds[2 * c + 0], -1.0f), 1.0f);
        float gy = fminf(fmaxf(ry + off_lds[2 * c + 1], -1.0f), 1.0f);
        float ix = (gx + 1.0f) * (0.5f * W_) - 0.5f;
        float iy = (gy + 1.0f) * (0.5f * H_) - 0.5f;
        float x0f = floorf(ix), y0f = floorf(iy);
        int x0 = (int)x0f, y0 = (int)y0f;
        int x1 = x0 + 1,  y1 = y0 + 1;
        float wx1 = ix - x0f, wx0 = 1.0f - wx1;
        float wy1 = iy - y0f, wy0 = 1.0f - wy1;
        float v00 = (float)((x0 >= 0) && (x0 < W_) && (y0 >= 0) && (y0 < H_));
        float v10 = (float)((x1 >= 0) && (x1 < W_) && (y0 >= 0) && (y0 < H_));
        float v01 = (float)((x0 >= 0) && (x0 < W_) && (y1 >= 0) && (y1 < H_));
        float v11 = (float)((x1 >= 0) && (x1 < W_) && (y1 >= 0) && (y1 < H_));
        int x0c = min(max(x0, 0), W_ - 1), x1c = min(max(x1, 0), W_ - 1);
        int y0c = min(max(y0, 0), H_ - 1), y1c = min(max(y1, 0), H_ - 1);
        const int mi = bj * HP_ + c;
        meta_idx[mi] = make_int4(y0c * W_ + x0c, y0c * W_ + x1c,
                                 y1c * W_ + x0c, y1c * W_ + x1c);
        meta_w[mi] = make_float4(ww * wx0 * wy0 * v00, ww * wx1 * wy0 * v10,
                                 ww * wx0 * wy1 * v01, ww * wx1 * wy1 * v11);
    }
}

// ---------------------------------------------------------------------------
// Pass 3: per (b, 4-channel group), 512 threads — global_load_lds staging of
// 4 planes (64 KB), meta prefetched to registers, gather + shuffle reduce.
// Round-6 proven structure + wave-uniform skip of dead iter-1 waves.
// ---------------------------------------------------------------------------
__global__ __launch_bounds__(512, 2)
void gather_kernel(const float* __restrict__ feat,      // [B,C,H,W]
                   const int4*  __restrict__ meta_idx,  // [B*J*HP]
                   const float4* __restrict__ meta_w,   // [B*J*HP]
                   float* __restrict__ acc)             // [B,J,C]
{
    __shared__ float plane[CG_ * HW_];   // 64 KB

    const int blk = blockIdx.x;
    const int b   = blk >> 6;       // / (C_/CG_) = /64
    const int cg  = blk & 63;
    const int c0  = cg * CG_;
    const int t   = threadIdx.x;
    const int wv  = t >> 6;         // wave 0..7
    const int ln  = t & 63;

    // ---- stage 4 planes (16384 floats = 64 KB) via global_load_lds w=16 ----
    {
        const char* gsrc = (const char*)(feat + (size_t)(b * C_ + c0) * HW_);
        #pragma unroll
        for (int i = 0; i < 8; ++i) {
            const size_t off = ((size_t)(i * 512 + wv * 64)) * 16;
            __builtin_amdgcn_global_load_lds(
                (const __attribute__((address_space(1))) void*)(gsrc + off + (size_t)ln * 16),
                (__attribute__((address_space(3))) void*)((char*)plane + off),
                16, 0, 0);
        }
    }

    // ---- prefetch meta while loads drain (wave-uniform skip of dead waves) --
    const int p    = ln & 31;
    const int half = ln >> 5;
    int4   id_r[2];
    float4 w_r[2];
    #pragma unroll
    for (int iter = 0; iter < 2; ++iter) {
        const int jbase = iter * 16 + wv * 2;   // wave-uniform
        id_r[iter] = make_int4(0, 0, 0, 0);
        w_r[iter]  = make_float4(0.f, 0.f, 0.f, 0.f);
        if (jbase < J_) {                        // skip fully-dead waves
            const int j = jbase + half;
            if (j < J_) {
                const int mi = (b * J_ + j) * HP_ + p;
                id_r[iter] = meta_idx[mi];
                w_r[iter]  = meta_w[mi];
            }
        }
    }
    __syncthreads();   // drains vmcnt (global_load_lds) + barrier

    #pragma unroll
    for (int iter = 0; iter < 2; ++iter) {
        const int jbase = iter * 16 + wv * 2;   // wave-uniform
        if (jbase >= J_) continue;               // whole wave idle: skip body
        const int j = jbase + half;
        const int4   id = id_r[iter];
        const float4 w  = w_r[iter];
        float pj0 = w.x * plane[0 * HW_ + id.x] + w.y * plane[0 * HW_ + id.y]
                  + w.z * plane[0 * HW_ + id.z] + w.w * plane[0 * HW_ + id.w];
        float pj1 = w.x * plane[1 * HW_ + id.x] + w.y * plane[1 * HW_ + id.y]
                  + w.z * plane[1 * HW_ + id.z] + w.w * plane[1 * HW_ + id.w];
        float pj2 = w.x * plane[2 * HW_ + id.x] + w.y * plane[2 * HW_ + id.y]
                  + w.z * plane[2 * HW_ + id.z] + w.w * plane[2 * HW_ + id.w];
        float pj3 = w.x * plane[3 * HW_ + id.x] + w.y * plane[3 * HW_ + id.y]
                  + w.z * plane[3 * HW_ + id.z] + w.w * plane[3 * HW_ + id.w];
        #pragma unroll
        for (int mask = 16; mask >= 1; mask >>= 1) {
            pj0 += __shfl_xor(pj0, mask);
            pj1 += __shfl_xor(pj1, mask);
            pj2 += __shfl_xor(pj2, mask);
            pj3 += __shfl_xor(pj3, mask);
        }
        if (j < J_ && p == 0) {
            float4* dst = (float4*)(acc + ((size_t)(b * J_ + j)) * C_ + c0);
            *dst = make_float4(pj0, pj1, pj2, pj3);
        }
    }
}

// ---------------------------------------------------------------------------
// Pass 4: tiled output projection — 8 bj rows per block, Wout reuse x8.
// ---------------------------------------------------------------------------
__global__ __launch_bounds__(256)
void proj_kernel(const float* __restrict__ acc,   // [B*J, C]
                 const float* __restrict__ Wout,  // [C, C]
                 const float* __restrict__ bout,  // [C]
                 float* __restrict__ out)         // [B*J, C]
{
    __shared__ float a_lds[PROJ_ROWS][C_];
    const int bj0 = blockIdx.x * PROJ_ROWS;
    const int t   = threadIdx.x;

    #pragma unroll
    for (int r = 0; r < PROJ_ROWS; ++r)
        a_lds[r][t] = acc[(size_t)(bj0 + r) * C_ + t];
    __syncthreads();

    float o[PROJ_ROWS];
    const float bb = bout[t];
    #pragma unroll
    for (int r = 0; r < PROJ_ROWS; ++r) o[r] = bb;
    #pragma unroll 4
    for (int k = 0; k < C_; ++k) {
        const float wvv = Wout[(size_t)k * C_ + t];
        #pragma unroll
        for (int r = 0; r < PROJ_ROWS; ++r)
            o[r] += a_lds[r][k] * wvv;
    }
    #pragma unroll
    for (int r = 0; r < PROJ_ROWS; ++r)
        out[(size_t)(bj0 + r) * C_ + t] = o[r];
}

extern "C" void kernel_launch(void* const* d_in, const int* in_sizes, int n_in,
                              void* d_out, int out_size, void* d_ws, size_t ws_size,
                              hipStream_t stream) {
    const float* feat   = (const float*)d_in[0];
    const float* refpts = (const float*)d_in[1];
    const float* Woff   = (const float*)d_in[2];
    const float* boff   = (const float*)d_in[3];
    const float* Ww     = (const float*)d_in[4];
    const float* bw     = (const float*)d_in[5];
    const float* Wout   = (const float*)d_in[6];
    const float* bout   = (const float*)d_in[7];
    float* out = (float*)d_out;

    const size_t n_meta    = (size_t)B_ * J_ * HP_;
    const size_t idx_bytes = n_meta * sizeof(int4);
    const size_t w_bytes   = n_meta * sizeof(float4);

    char* ws = (char*)d_ws;
    int4*   meta_idx = (int4*)ws;
    float4* meta_w   = (float4*)(ws + idx_bytes);
    float*  acc      = (float*)(ws + idx_bytes + w_bytes);

    pass12_kernel<<<dim3(B_ * J_), dim3(256), 0, stream>>>(
        feat, refpts, Woff, boff, Ww, bw, meta_idx, meta_w);
    gather_kernel<<<dim3(B_ * (C_ / CG_)), dim3(512), 0, stream>>>(
        feat, meta_idx, meta_w, acc);
    proj_kernel<<<dim3((B_ * J_) / PROJ_ROWS), dim3(256), 0, stream>>>(
        acc, Wout, bout, out);
}